// Round 1
// baseline (3032.519 us; speedup 1.0000x reference)
//
#include <hip/hip_runtime.h>

// LSTM decoder, MI355X. Persistent recurrence, round 6.
// Sync fabric v3: per-block step-tagged flags (store-only, no atomic RMW),
// parallel per-thread polling, single sync layer per step. h(t-1) is read
// directly from the global double buffer through own-XCD L2 after a
// buffer_inv sc0 sc1 (all k_rnn global stores are write-through coherent,
// so L2 never holds dirty lines and the inv is loss-free).
// L=128, B=64, IN_F=ACT_F=512, H=1024.

#define LSTEPS 128
#define B 64
#define ACTF 512
#define H 1024
#define NB 128             // persistent blocks, co-resident (1/CU at ~104KB LDS)
#define HC 8               // h-columns per block
#define GSTR 33            // LDS gate tile leading-dim pad

typedef short s16x8 __attribute__((ext_vector_type(8)));   // 8 x bf16
typedef short s16x4 __attribute__((ext_vector_type(4)));   // 4 x bf16
typedef float f32x4 __attribute__((ext_vector_type(4)));
typedef unsigned short u16;
typedef unsigned long long u64;

__device__ __forceinline__ u16 f2bf(float f) {
  return __builtin_bit_cast(u16, (__bf16)f);   // RNE
}
__device__ __forceinline__ float sigm(float x) { return 1.f / (1.f + __expf(-x)); }
__device__ __forceinline__ float tanh_fast(float x) { return 2.f / (1.f + __expf(-2.f * x)) - 1.f; }

// coherent (write-through, L1/L2-bypassing) accessors
__device__ __forceinline__ void st16_coh(void* p, f32x4 v) {
  asm volatile("global_store_dwordx4 %0, %1, off sc0 sc1" :: "v"(p), "v"(v) : "memory");
}
__device__ __forceinline__ void st8_coh(void* p, u64 v) {
  asm volatile("global_store_dwordx2 %0, %1, off sc0 sc1" :: "v"(p), "v"(v) : "memory");
}
__device__ __forceinline__ void st4_coh(void* p, unsigned v) {
  asm volatile("global_store_dword %0, %1, off sc0 sc1" :: "v"(p), "v"(v) : "memory");
}
__device__ __forceinline__ unsigned ld4_coh(const void* p) {
  unsigned v;
  asm volatile("global_load_dword %0, %1, off sc0 sc1\n\ts_waitcnt vmcnt(0)"
               : "=v"(v) : "v"(p) : "memory");
  return v;
}

// ---- merged setup kernel: role by block range (unchanged) ----
__global__ void k_setup(const float* __restrict__ act, u16* __restrict__ actb,
                        const float* __restrict__ Wih, const float* __restrict__ Whh,
                        u16* __restrict__ wg,
                        const float* __restrict__ h0, u16* __restrict__ hbf,
                        unsigned* __restrict__ scnt, unsigned* __restrict__ xcnt,
                        unsigned* __restrict__ xctr,
                        const float* __restrict__ inf, const float* __restrict__ bih,
                        const float* __restrict__ bhh, float* __restrict__ pre0) {
  const int bb = blockIdx.x;
  const int tid = threadIdx.x;
  if (bb < 2048) {                                   // act fp32 -> bf16
    int id = bb * 256 + tid;
    const float4* s = (const float4*)act + (size_t)id * 2;
    float4 a = s[0], b = s[1];
    s16x8 o;
    o[0] = (short)f2bf(a.x); o[1] = (short)f2bf(a.y); o[2] = (short)f2bf(a.z); o[3] = (short)f2bf(a.w);
    o[4] = (short)f2bf(b.x); o[5] = (short)f2bf(b.y); o[6] = (short)f2bf(b.z); o[7] = (short)f2bf(b.w);
    *((s16x8*)actb + id) = o;
  } else if (bb < 5120) {                            // W fragments (B-frag contiguous)
    int idx = (bb - 2048) * 256 + tid;
    int bk = idx / 6144;
    int lin = idx - bk * 6144;
    int kt = lin >> 7, T = (lin >> 6) & 1, lane = lin & 63;
    int q = lane >> 4, r = lane & 15;
    int local = T * 16 + r;
    int j = (local >> 3) * 1024 + bk * 8 + (local & 7);
    int k = kt * 32 + q * 8;
    const float* src = (k < 512) ? (Wih + (size_t)j * 1024 + 512 + k)
                                 : (Whh + (size_t)j * 1024 + (k - 512));
    s16x8 o;
#pragma unroll
    for (int e = 0; e < 8; ++e) o[e] = (short)f2bf(src[e]);
    ((s16x8*)wg)[(size_t)bk * 6144 + lin] = o;
  } else if (bb < 5152) {                            // h0 -> bf16 into hbf[1] + zero flags
    int id = (bb - 5120) * 256 + tid;                // 0..8191, 8 elems each
    const float4* s = (const float4*)h0 + (size_t)id * 2;
    float4 a = s[0], b = s[1];
    s16x8 o;
    o[0] = (short)f2bf(a.x); o[1] = (short)f2bf(a.y); o[2] = (short)f2bf(a.z); o[3] = (short)f2bf(a.w);
    o[4] = (short)f2bf(b.x); o[5] = (short)f2bf(b.y); o[6] = (short)f2bf(b.z); o[7] = (short)f2bf(b.w);
    *((s16x8*)(hbf + 65536) + id) = o;
    if (bb == 5120) {
      if (tid == 0) scnt[0] = 0u;
      if (tid < 128) xcnt[tid] = 0u;                 // xcnt region doubles as flag array
      if (tid < 8) xctr[tid] = 0u;
    }
  } else {                                           // PRE0 = IF@Wih[:,:512]^T + b_ih + b_hh
    int o = (bb - 5152) * 256 + tid;
    int bk = o >> 11;
    int rr = o & 2047;
    int b = rr >> 5;
    int local = rr & 31;
    int j = (local >> 3) * 1024 + bk * 8 + (local & 7);
    const float4* xa = (const float4*)(inf + (size_t)b * 512);
    const float4* wa = (const float4*)(Wih + (size_t)j * 1024);
    float s = 0.f;
#pragma unroll 4
    for (int k = 0; k < 128; ++k) {
      float4 x = xa[k], w = wa[k];
      s += x.x * w.x + x.y * w.y + x.z * w.z + x.w * w.w;
    }
    pre0[o] = s + bih[j] + bhh[j];
  }
}

// ---- persistent recurrent kernel ----
__global__ void __launch_bounds__(256, 1) k_rnn(
    const u16* __restrict__ actb, const u16* __restrict__ wg,
    const float* __restrict__ pre0, const float* __restrict__ cinit,
    u16* __restrict__ hbf, unsigned* __restrict__ flags,
    float* __restrict__ out) {
  extern __shared__ char smem[];
  u16* wlds = (u16*)smem;                 // 98304 B: W fragments (persistent)
  float* gl = (float*)(smem + 98304);     // 64 x 33 fp32 gate tile

  const int tid = threadIdx.x;
  const int bk = blockIdx.x;
  const int w = tid >> 6;
  const int lane = tid & 63;
  const int q = lane >> 4, r = lane & 15;
  const int n0 = bk * HC;

  {
    const s16x8* src = (const s16x8*)wg + (size_t)bk * 6144;
    s16x8* dst = (s16x8*)wlds;
    for (int i = tid; i < 6144; i += 256) dst[i] = src[i];
  }

  // pointwise ownership: tid<128 -> (row=tid>>1, 4 adjacent cols)
  const int prow = tid >> 1, pcg = (tid & 1) * 4;
  float pr4[16], cr[4];
  if (tid < 128) {
#pragma unroll
    for (int g = 0; g < 4; ++g)
#pragma unroll
      for (int e = 0; e < 4; ++e)
        pr4[g * 4 + e] = pre0[bk * 2048 + prow * 32 + g * 8 + pcg + e];
#pragma unroll
    for (int e = 0; e < 4; ++e) cr[e] = cinit[prow * H + n0 + pcg + e];
  }

  __syncthreads();

  for (int t = 0; t < LSTEPS; ++t) {
    const int par = (t - 1) & 1;               // parity of h(t-1) buffer

    // phase 1: zero gate tile (pre0 is added in the pointwise from registers)
#pragma unroll
    for (int j = 0; j < 8; ++j) {
      int i = j * 256 + tid;
      gl[(i >> 5) * GSTR + (i & 31)] = 0.f;
    }

    f32x4 acc[4][2];
#pragma unroll
    for (int mt = 0; mt < 4; ++mt) {
      f32x4 z = {0.f, 0.f, 0.f, 0.f};
      acc[mt][0] = z; acc[mt][1] = z;
    }

    // phase 2: act-part MFMAs (independent of h(t-1)) — overlap the wait;
    // their L3 refills (post-inv) hide under the flag poll below.
    const u16* atb = actb + (size_t)t * (B * ACTF);
#pragma unroll
    for (int kk = 0; kk < 4; ++kk) {
      const int kt = w * 4 + kk;
      const int k = kt * 32 + q * 8;
      const s16x8* wb = (const s16x8*)wlds + kt * 128;
      s16x8 bf0 = wb[lane];
      s16x8 bf1 = wb[64 + lane];
#pragma unroll
      for (int mt = 0; mt < 4; ++mt) {
        const int m = mt * 16 + r;
        s16x8 af = *(const s16x8*)(atb + m * ACTF + k);
        acc[mt][0] = __builtin_amdgcn_mfma_f32_16x16x32_bf16(af, bf0, acc[mt][0], 0, 0, 0);
        acc[mt][1] = __builtin_amdgcn_mfma_f32_16x16x32_bf16(af, bf1, acc[mt][1], 0, 0, 0);
      }
    }

    // phase 3: wait for all 128 h(t-1) publications — per-block step-tagged
    // flags, polled in parallel (no atomic RMW anywhere on the hot path).
    if (t) {
      if (tid < NB) {
        unsigned g = 0;
        while (ld4_coh(flags + tid) < (unsigned)t) {
          __builtin_amdgcn_s_sleep(1);
          if (++g > (1u << 18)) break;   // bounded spin: wrong-answer beats hang
        }
      }
      __syncthreads();
    }
    // drop all (clean-by-construction) L1/L2 lines so plain loads see the
    // write-through h(t-1); the 16 blocks/XCD then MSHR-merge into one
    // L3->L2 broadcast pull of the 128KB h buffer.
    asm volatile("buffer_inv sc0 sc1" ::: "memory");

    // phase 4: h-part MFMAs, plain cached loads straight from hbf
    const u16* hsrc = hbf + par * 65536;
#pragma unroll
    for (int kk = 0; kk < 8; ++kk) {
      const int kt = 16 + w * 8 + kk;
      const int k = kt * 32 + q * 8;
      const s16x8* wb = (const s16x8*)wlds + kt * 128;
      s16x8 bf0 = wb[lane];
      s16x8 bf1 = wb[64 + lane];
#pragma unroll
      for (int mt = 0; mt < 4; ++mt) {
        const int m = mt * 16 + r;
        s16x8 af = *(const s16x8*)(hsrc + m * H + (k - ACTF));
        acc[mt][0] = __builtin_amdgcn_mfma_f32_16x16x32_bf16(af, bf0, acc[mt][0], 0, 0, 0);
        acc[mt][1] = __builtin_amdgcn_mfma_f32_16x16x32_bf16(af, bf1, acc[mt][1], 0, 0, 0);
      }
    }

    // phase 5: cross-wave K reduction into gate tile
#pragma unroll
    for (int mt = 0; mt < 4; ++mt) {
      const int bb2 = mt * 16 + q * 4;
#pragma unroll
      for (int T = 0; T < 2; ++T) {
        const int lc = T * 16 + r;
#pragma unroll
        for (int e = 0; e < 4; ++e)
          atomicAdd(&gl[(bb2 + e) * GSTR + lc], acc[mt][T][e]);
      }
    }
    __syncthreads();

    // phase 6: pointwise (tid<128: one row, 4 adjacent cols) + publication.
    // NOTE: every global store here is write-through coherent so buffer_inv
    // can never drop dirty data.
    if (tid < 128) {
      float hv[4];
#pragma unroll
      for (int e = 0; e < 4; ++e) {
        const int c = pcg + e;
        float ig = sigm(gl[prow * GSTR + c] + pr4[e]);
        float fg = sigm(gl[prow * GSTR + 8 + c] + pr4[4 + e]);
        float gg = tanh_fast(gl[prow * GSTR + 16 + c] + pr4[8 + e]);
        float og = sigm(gl[prow * GSTR + 24 + c] + pr4[12 + e]);
        cr[e] = fg * cr[e] + ig * gg;
        hv[e] = og * tanh_fast(cr[e]);
      }
      f32x4 hv4; hv4[0] = hv[0]; hv4[1] = hv[1]; hv4[2] = hv[2]; hv4[3] = hv[3];
      float* oaddr = out + (size_t)t * (B * H) + prow * H + n0 + pcg;
      st16_coh(oaddr, hv4);
      if (t < LSTEPS - 1) {
        s16x4 hb; hb[0] = (short)f2bf(hv[0]); hb[1] = (short)f2bf(hv[1]);
        hb[2] = (short)f2bf(hv[2]); hb[3] = (short)f2bf(hv[3]);
        st8_coh(hbf + (t & 1) * 65536 + prow * H + n0 + pcg, __builtin_bit_cast(u64, hb));
      } else {
        float* hn = out + (size_t)LSTEPS * (B * H);
        float* cn = hn + B * H;
        f32x4 cr4; cr4[0] = cr[0]; cr4[1] = cr[1]; cr4[2] = cr[2]; cr4[3] = cr[3];
        st16_coh(hn + prow * H + n0 + pcg, hv4);
        st16_coh(cn + prow * H + n0 + pcg, cr4);
      }
    }

    // publish: drain own h stores, block-join, set this block's flag (store,
    // not RMW — 128 independent words, monotone tags, no reset needed)
    if (t < LSTEPS - 1) {
      asm volatile("s_waitcnt vmcnt(0)" ::: "memory");
      __syncthreads();
      if (tid == 0) st4_coh(flags + bk, (unsigned)(t + 1));
    }
  }
}

extern "C" void kernel_launch(void* const* d_in, const int* in_sizes, int n_in,
                              void* d_out, int out_size, void* d_ws, size_t ws_size,
                              hipStream_t stream) {
  const float* inf = (const float*)d_in[0];
  const float* act = (const float*)d_in[1];
  const float* h0  = (const float*)d_in[2];
  const float* cst = (const float*)d_in[3];
  const float* Wih = (const float*)d_in[4];
  const float* Whh = (const float*)d_in[5];
  const float* bih = (const float*)d_in[6];
  const float* bhh = (const float*)d_in[7];
  float* out = (float*)d_out;

  char* ws = (char*)d_ws;
  u16* actb      = (u16*)ws;                    //  8,388,608 B
  u16* wg        = (u16*)(ws + 8388608);        // 12,582,912 B
  float* pre0    = (float*)(ws + 20971520);     //  1,048,576 B
  u16* hbf       = (u16*)(ws + 22020096);       //    262,144 B (2 parity x 64x1024 bf16)
  unsigned* scn  = (unsigned*)(ws + 24379392);  //         64 B (unused this round)
  unsigned* flg  = (unsigned*)(ws + 24379456);  //        512 B (128 per-block flags)
  unsigned* xct  = (unsigned*)(ws + 24379968);  //         32 B (unused this round)

  hipLaunchKernelGGL(k_setup, dim3(6176), dim3(256), 0, stream,
                     act, actb, Wih, Whh, wg, h0, hbf, scn, flg, xct,
                     inf, bih, bhh, pre0);

  hipFuncSetAttribute((const void*)k_rnn, hipFuncAttributeMaxDynamicSharedMemorySize, 106752);
  hipLaunchKernelGGL(k_rnn, dim3(NB), dim3(256), 106752, stream,
                     actb, wg, pre0, cst, hbf, flg, out);
}

// Round 2
// 2513.250 us; speedup vs baseline: 1.2066x; 1.2066x over previous
//
#include <hip/hip_runtime.h>

// LSTM decoder, MI355X. Persistent recurrence, round 7.
// DPM experiment + fabric simplification:
//  - NO s_sleep anywhere; waves 1-3 burn VALU (dependent fmac chains) while
//    polling an LDS tag -> keeps SCLK up if DPM downclock is the 20us/step
//    mystery.
//  - NO buffer_inv: h(t-1) is read with coherent (sc0 sc1) loads directly,
//    double-buffered in registers with counted vmcnt(4). L2 stays warm for
//    actb/wg/pre0 across the whole kernel.
//  - out stores are PLAIN cached stores (L2 merges into full lines).
//  - publish chain: coherent h-store -> vmcnt(0) -> barrier -> flag store.
// L=128, B=64, IN_F=ACT_F=512, H=1024.

#define LSTEPS 128
#define B 64
#define ACTF 512
#define H 1024
#define NB 128             // persistent blocks, co-resident (1/CU at ~104KB LDS)
#define HC 8               // h-columns per block
#define GSTR 33            // LDS gate tile leading-dim pad

typedef short s16x8 __attribute__((ext_vector_type(8)));   // 8 x bf16
typedef short s16x4 __attribute__((ext_vector_type(4)));   // 4 x bf16
typedef float f32x4 __attribute__((ext_vector_type(4)));
typedef unsigned short u16;
typedef unsigned long long u64;

__device__ __forceinline__ u16 f2bf(float f) {
  return __builtin_bit_cast(u16, (__bf16)f);   // RNE
}
__device__ __forceinline__ float sigm(float x) { return 1.f / (1.f + __expf(-x)); }
__device__ __forceinline__ float tanh_fast(float x) { return 2.f / (1.f + __expf(-2.f * x)) - 1.f; }

// coherent (cache-bypassing, cross-XCD-visible) accessors
__device__ __forceinline__ void st8_coh(void* p, u64 v) {
  asm volatile("global_store_dwordx2 %0, %1, off sc0 sc1" :: "v"(p), "v"(v) : "memory");
}
__device__ __forceinline__ void st4_coh(void* p, unsigned v) {
  asm volatile("global_store_dword %0, %1, off sc0 sc1" :: "v"(p), "v"(v) : "memory");
}
__device__ __forceinline__ u64 ld8_coh(const void* p) {
  u64 v;
  asm volatile("global_load_dwordx2 %0, %1, off sc0 sc1\n\ts_waitcnt vmcnt(0)"
               : "=v"(v) : "v"(p) : "memory");
  return v;
}

// ---- merged setup kernel: role by block range (unchanged) ----
__global__ void k_setup(const float* __restrict__ act, u16* __restrict__ actb,
                        const float* __restrict__ Wih, const float* __restrict__ Whh,
                        u16* __restrict__ wg,
                        const float* __restrict__ h0, u16* __restrict__ hbf,
                        unsigned* __restrict__ scnt, unsigned* __restrict__ xcnt,
                        unsigned* __restrict__ xctr,
                        const float* __restrict__ inf, const float* __restrict__ bih,
                        const float* __restrict__ bhh, float* __restrict__ pre0) {
  const int bb = blockIdx.x;
  const int tid = threadIdx.x;
  if (bb < 2048) {                                   // act fp32 -> bf16
    int id = bb * 256 + tid;
    const float4* s = (const float4*)act + (size_t)id * 2;
    float4 a = s[0], b = s[1];
    s16x8 o;
    o[0] = (short)f2bf(a.x); o[1] = (short)f2bf(a.y); o[2] = (short)f2bf(a.z); o[3] = (short)f2bf(a.w);
    o[4] = (short)f2bf(b.x); o[5] = (short)f2bf(b.y); o[6] = (short)f2bf(b.z); o[7] = (short)f2bf(b.w);
    *((s16x8*)actb + id) = o;
  } else if (bb < 5120) {                            // W fragments (B-frag contiguous)
    int idx = (bb - 2048) * 256 + tid;
    int bk = idx / 6144;
    int lin = idx - bk * 6144;
    int kt = lin >> 7, T = (lin >> 6) & 1, lane = lin & 63;
    int q = lane >> 4, r = lane & 15;
    int local = T * 16 + r;
    int j = (local >> 3) * 1024 + bk * 8 + (local & 7);
    int k = kt * 32 + q * 8;
    const float* src = (k < 512) ? (Wih + (size_t)j * 1024 + 512 + k)
                                 : (Whh + (size_t)j * 1024 + (k - 512));
    s16x8 o;
#pragma unroll
    for (int e = 0; e < 8; ++e) o[e] = (short)f2bf(src[e]);
    ((s16x8*)wg)[(size_t)bk * 6144 + lin] = o;
  } else if (bb < 5152) {                            // h0 -> bf16 into hbf[1] + zero flags
    int id = (bb - 5120) * 256 + tid;                // 0..8191, 8 elems each
    const float4* s = (const float4*)h0 + (size_t)id * 2;
    float4 a = s[0], b = s[1];
    s16x8 o;
    o[0] = (short)f2bf(a.x); o[1] = (short)f2bf(a.y); o[2] = (short)f2bf(a.z); o[3] = (short)f2bf(a.w);
    o[4] = (short)f2bf(b.x); o[5] = (short)f2bf(b.y); o[6] = (short)f2bf(b.z); o[7] = (short)f2bf(b.w);
    *((s16x8*)(hbf + 65536) + id) = o;
    if (bb == 5120) {
      if (tid == 0) scnt[0] = 0u;
      if (tid < 128) xcnt[tid] = 0u;                 // xcnt region doubles as flag array
      if (tid < 8) xctr[tid] = 0u;
    }
  } else {                                           // PRE0 = IF@Wih[:,:512]^T + b_ih + b_hh
    int o = (bb - 5152) * 256 + tid;
    int bk = o >> 11;
    int rr = o & 2047;
    int b = rr >> 5;
    int local = rr & 31;
    int j = (local >> 3) * 1024 + bk * 8 + (local & 7);
    const float4* xa = (const float4*)(inf + (size_t)b * 512);
    const float4* wa = (const float4*)(Wih + (size_t)j * 1024);
    float s = 0.f;
#pragma unroll 4
    for (int k = 0; k < 128; ++k) {
      float4 x = xa[k], w = wa[k];
      s += x.x * w.x + x.y * w.y + x.z * w.z + x.w * w.w;
    }
    pre0[o] = s + bih[j] + bhh[j];
  }
}

// ---- persistent recurrent kernel ----
__global__ void __launch_bounds__(256, 1) k_rnn(
    const u16* __restrict__ actb, const u16* __restrict__ wg,
    const float* __restrict__ pre0, const float* __restrict__ cinit,
    u16* __restrict__ hbf, unsigned* __restrict__ flags,
    float* __restrict__ out) {
  extern __shared__ char smem[];
  u16* wlds = (u16*)smem;                 // 98304 B: W fragments (persistent)
  float* gl = (float*)(smem + 98304);     // 64 x 33 fp32 gate tile
  __shared__ int sdone;                   // monotone step tag: wave0 -> burn waves

  const int tid = threadIdx.x;
  const int bk = blockIdx.x;
  const int w = tid >> 6;
  const int lane = tid & 63;
  const int q = lane >> 4, r = lane & 15;
  const int n0 = bk * HC;

  {
    const s16x8* src = (const s16x8*)wg + (size_t)bk * 6144;
    s16x8* dst = (s16x8*)wlds;
    for (int i = tid; i < 6144; i += 256) dst[i] = src[i];
  }

  // pointwise ownership: tid<128 -> (row=tid>>1, 4 adjacent cols)
  const int prow = tid >> 1, pcg = (tid & 1) * 4;
  float pr4[16], cr[4];
  if (tid < 128) {
#pragma unroll
    for (int g = 0; g < 4; ++g)
#pragma unroll
      for (int e = 0; e < 4; ++e)
        pr4[g * 4 + e] = pre0[bk * 2048 + prow * 32 + g * 8 + pcg + e];
#pragma unroll
    for (int e = 0; e < 4; ++e) cr[e] = cinit[prow * H + n0 + pcg + e];
  }
  if (tid == 0) sdone = 0;

  __syncthreads();

  for (int t = 0; t < LSTEPS; ++t) {
    const int par = (t - 1) & 1;               // parity of h(t-1) buffer

    // phase 1: zero gate tile (pre0 is added in the pointwise from registers)
#pragma unroll
    for (int j = 0; j < 8; ++j) {
      int i = j * 256 + tid;
      gl[(i >> 5) * GSTR + (i & 31)] = 0.f;
    }

    f32x4 acc[4][2];
#pragma unroll
    for (int mt = 0; mt < 4; ++mt) {
      f32x4 z = {0.f, 0.f, 0.f, 0.f};
      acc[mt][0] = z; acc[mt][1] = z;
    }

    // phase 2: act-part MFMAs (independent of h(t-1)) — overlap the wait
    const u16* atb = actb + (size_t)t * (B * ACTF);
#pragma unroll
    for (int kk = 0; kk < 4; ++kk) {
      const int kt = w * 4 + kk;
      const int k = kt * 32 + q * 8;
      const s16x8* wb = (const s16x8*)wlds + kt * 128;
      s16x8 bf0 = wb[lane];
      s16x8 bf1 = wb[64 + lane];
#pragma unroll
      for (int mt = 0; mt < 4; ++mt) {
        const int m = mt * 16 + r;
        s16x8 af = *(const s16x8*)(atb + m * ACTF + k);
        acc[mt][0] = __builtin_amdgcn_mfma_f32_16x16x32_bf16(af, bf0, acc[mt][0], 0, 0, 0);
        acc[mt][1] = __builtin_amdgcn_mfma_f32_16x16x32_bf16(af, bf1, acc[mt][1], 0, 0, 0);
      }
    }

    // phase 3: wait for all 128 h(t-1) publications.
    // wave 0: tight coherent poll (2 flags/lane, one dwordx2 each, no sleep).
    // waves 1-3: VALU burn (clock-keeper) while polling LDS tag.
    if (t) {
      if (w == 0) {
        const unsigned* fp = flags + 2 * lane;
        unsigned g = 0;
        for (;;) {
          u64 v = ld8_coh(fp);
          if ((unsigned)v >= (unsigned)t && (unsigned)(v >> 32) >= (unsigned)t) break;
          if (++g > (1u << 20)) break;   // bounded spin: wrong-answer beats hang
        }
        if (tid == 0) *(volatile int*)&sdone = t;
      } else {
        float b0 = 1.0f + (float)lane * 1e-7f;
        float b1 = 1.0000001f;
        for (;;) {
#pragma unroll
          for (int u = 0; u < 32; ++u)
            asm volatile("v_fmac_f32 %0, %1, %2" : "+v"(b0) : "v"(b1), "v"(b1));
          if (*(volatile int*)&sdone >= t) break;
        }
        asm volatile("" :: "v"(b0));     // keep the burn chain live
      }
    }
    __syncthreads();

    // phase 4: h-part MFMAs; h(t-1) via coherent loads, double-buffered in
    // registers with counted vmcnt. No cache invalidates anywhere.
    const u16* hsrc = hbf + par * 65536;
    const u16* hp0 = hsrc + r * H + ((16 + w * 8) * 32 + q * 8 - ACTF);
    s16x8 ha0, ha1, ha2, ha3, hb0, hb1, hb2, hb3;

#define HLOAD(d0, d1, d2, d3, KK) do {                                          \
      const u16* hp_ = hp0 + (KK) * 32;                                         \
      asm volatile("global_load_dwordx4 %0, %1, off sc0 sc1" : "=v"(d0)         \
                   : "v"((const void*)(hp_)) : "memory");                       \
      asm volatile("global_load_dwordx4 %0, %1, off sc0 sc1" : "=v"(d1)         \
                   : "v"((const void*)(hp_ + 16 * H)) : "memory");              \
      asm volatile("global_load_dwordx4 %0, %1, off sc0 sc1" : "=v"(d2)         \
                   : "v"((const void*)(hp_ + 32 * H)) : "memory");              \
      asm volatile("global_load_dwordx4 %0, %1, off sc0 sc1" : "=v"(d3)         \
                   : "v"((const void*)(hp_ + 48 * H)) : "memory");              \
    } while (0)

#define KSTEP(c0, c1, c2, c3, n0_, n1_, n2_, n3_, KK) {                         \
      const s16x8* wb_ = (const s16x8*)wlds + (16 + w * 8 + (KK)) * 128;        \
      s16x8 bf0_ = wb_[lane];                                                   \
      s16x8 bf1_ = wb_[64 + lane];                                              \
      if ((KK) < 7) { HLOAD(n0_, n1_, n2_, n3_, (KK) + 1); }                    \
      if ((KK) < 7) asm volatile("s_waitcnt vmcnt(4)" ::: "memory");            \
      else          asm volatile("s_waitcnt vmcnt(0)" ::: "memory");            \
      __builtin_amdgcn_sched_barrier(0);                                        \
      acc[0][0] = __builtin_amdgcn_mfma_f32_16x16x32_bf16(c0, bf0_, acc[0][0], 0, 0, 0); \
      acc[0][1] = __builtin_amdgcn_mfma_f32_16x16x32_bf16(c0, bf1_, acc[0][1], 0, 0, 0); \
      acc[1][0] = __builtin_amdgcn_mfma_f32_16x16x32_bf16(c1, bf0_, acc[1][0], 0, 0, 0); \
      acc[1][1] = __builtin_amdgcn_mfma_f32_16x16x32_bf16(c1, bf1_, acc[1][1], 0, 0, 0); \
      acc[2][0] = __builtin_amdgcn_mfma_f32_16x16x32_bf16(c2, bf0_, acc[2][0], 0, 0, 0); \
      acc[2][1] = __builtin_amdgcn_mfma_f32_16x16x32_bf16(c2, bf1_, acc[2][1], 0, 0, 0); \
      acc[3][0] = __builtin_amdgcn_mfma_f32_16x16x32_bf16(c3, bf0_, acc[3][0], 0, 0, 0); \
      acc[3][1] = __builtin_amdgcn_mfma_f32_16x16x32_bf16(c3, bf1_, acc[3][1], 0, 0, 0); \
    }

    HLOAD(ha0, ha1, ha2, ha3, 0);
    KSTEP(ha0, ha1, ha2, ha3, hb0, hb1, hb2, hb3, 0)
    KSTEP(hb0, hb1, hb2, hb3, ha0, ha1, ha2, ha3, 1)
    KSTEP(ha0, ha1, ha2, ha3, hb0, hb1, hb2, hb3, 2)
    KSTEP(hb0, hb1, hb2, hb3, ha0, ha1, ha2, ha3, 3)
    KSTEP(ha0, ha1, ha2, ha3, hb0, hb1, hb2, hb3, 4)
    KSTEP(hb0, hb1, hb2, hb3, ha0, ha1, ha2, ha3, 5)
    KSTEP(ha0, ha1, ha2, ha3, hb0, hb1, hb2, hb3, 6)
    KSTEP(hb0, hb1, hb2, hb3, ha0, ha1, ha2, ha3, 7)
#undef KSTEP
#undef HLOAD

    // phase 5: cross-wave K reduction into gate tile
#pragma unroll
    for (int mt = 0; mt < 4; ++mt) {
      const int bb2 = mt * 16 + q * 4;
#pragma unroll
      for (int T = 0; T < 2; ++T) {
        const int lc = T * 16 + r;
#pragma unroll
        for (int e = 0; e < 4; ++e)
          atomicAdd(&gl[(bb2 + e) * GSTR + lc], acc[mt][T][e]);
      }
    }
    __syncthreads();

    // phase 6: pointwise (tid<128: one row, 4 adjacent cols) + publication.
    // Coherent h-store FIRST (critical path), plain cached out store after.
    if (tid < 128) {
      float hv[4];
#pragma unroll
      for (int e = 0; e < 4; ++e) {
        const int c = pcg + e;
        float ig = sigm(gl[prow * GSTR + c] + pr4[e]);
        float fg = sigm(gl[prow * GSTR + 8 + c] + pr4[4 + e]);
        float gg = tanh_fast(gl[prow * GSTR + 16 + c] + pr4[8 + e]);
        float og = sigm(gl[prow * GSTR + 24 + c] + pr4[12 + e]);
        cr[e] = fg * cr[e] + ig * gg;
        hv[e] = og * tanh_fast(cr[e]);
      }
      if (t < LSTEPS - 1) {
        s16x4 hb; hb[0] = (short)f2bf(hv[0]); hb[1] = (short)f2bf(hv[1]);
        hb[2] = (short)f2bf(hv[2]); hb[3] = (short)f2bf(hv[3]);
        st8_coh(hbf + (t & 1) * 65536 + prow * H + n0 + pcg, __builtin_bit_cast(u64, hb));
      }
      f32x4 hv4; hv4[0] = hv[0]; hv4[1] = hv[1]; hv4[2] = hv[2]; hv4[3] = hv[3];
      *(f32x4*)(out + (size_t)t * (B * H) + prow * H + n0 + pcg) = hv4;  // plain
      if (t == LSTEPS - 1) {
        float* hn = out + (size_t)LSTEPS * (B * H);
        float* cn = hn + B * H;
        f32x4 cr4; cr4[0] = cr[0]; cr4[1] = cr[1]; cr4[2] = cr[2]; cr4[3] = cr[3];
        *(f32x4*)(hn + prow * H + n0 + pcg) = hv4;
        *(f32x4*)(cn + prow * H + n0 + pcg) = cr4;
      }
    }

    // publish: drain h stores, block-join, set this block's flag (store-only,
    // monotone tags, no reset needed)
    if (t < LSTEPS - 1) {
      asm volatile("s_waitcnt vmcnt(0)" ::: "memory");
      __syncthreads();
      if (tid == 0) st4_coh(flags + bk, (unsigned)(t + 1));
    }
  }
}

extern "C" void kernel_launch(void* const* d_in, const int* in_sizes, int n_in,
                              void* d_out, int out_size, void* d_ws, size_t ws_size,
                              hipStream_t stream) {
  const float* inf = (const float*)d_in[0];
  const float* act = (const float*)d_in[1];
  const float* h0  = (const float*)d_in[2];
  const float* cst = (const float*)d_in[3];
  const float* Wih = (const float*)d_in[4];
  const float* Whh = (const float*)d_in[5];
  const float* bih = (const float*)d_in[6];
  const float* bhh = (const float*)d_in[7];
  float* out = (float*)d_out;

  char* ws = (char*)d_ws;
  u16* actb      = (u16*)ws;                    //  8,388,608 B
  u16* wg        = (u16*)(ws + 8388608);        // 12,582,912 B
  float* pre0    = (float*)(ws + 20971520);     //  1,048,576 B
  u16* hbf       = (u16*)(ws + 22020096);       //    262,144 B (2 parity x 64x1024 bf16)
  unsigned* scn  = (unsigned*)(ws + 24379392);  //         64 B (unused this round)
  unsigned* flg  = (unsigned*)(ws + 24379456);  //        512 B (128 per-block flags)
  unsigned* xct  = (unsigned*)(ws + 24379968);  //         32 B (unused this round)

  hipLaunchKernelGGL(k_setup, dim3(6176), dim3(256), 0, stream,
                     act, actb, Wih, Whh, wg, h0, hbf, scn, flg, xct,
                     inf, bih, bhh, pre0);

  hipFuncSetAttribute((const void*)k_rnn, hipFuncAttributeMaxDynamicSharedMemorySize, 106752);
  hipLaunchKernelGGL(k_rnn, dim3(NB), dim3(256), 106752, stream,
                     actb, wg, pre0, cst, hbf, flg, out);
}